// Round 1
// baseline (307.428 us; speedup 1.0000x reference)
//
#include <hip/hip_runtime.h>

constexpr int B = 8, C = 128, H = 64, W = 64, O = 128;
constexpr int K2 = 9;
constexpr int HW = H * W; // 4096
constexpr int CC = 32;    // c-chunk in kernel 2

// ---------------- kernel 0: weight transpose ----------------
// wT[k][c][o] = weight[o][c][k]
__global__ void wtrans_kernel(const float* __restrict__ w, float* __restrict__ wT) {
    int idx = blockIdx.x * 256 + threadIdx.x; // [0, 9*128*128)
    int o = idx & 127;
    int c = (idx >> 7) & 127;
    int k = idx >> 14;
    wT[idx] = w[(o * C + c) * 9 + k];
}

// ---------------- kernel 1: offset conv (18 channels, pad=1) ----------------
// offs[b][ch][y][x]; grid: B*6*(H/4) blocks of 256 (4 rows x 64 cols), 3 oc per block
__global__ __launch_bounds__(256) void offconv_kernel(
    const float* __restrict__ x, const float* __restrict__ ow,
    const float* __restrict__ ob, float* __restrict__ offs) {
    __shared__ float ws[3 * C * 9]; // 3456 floats
    int t = threadIdx.x;
    int bid = blockIdx.x;
    int ytile = bid & 15;       // H/4 = 16
    int ocg = (bid >> 4) % 6;
    int b = bid / (6 * 16);
    int oc0 = ocg * 3;
    for (int i = t; i < 3 * C * 9; i += 256) ws[i] = ow[oc0 * C * 9 + i];
    __syncthreads();
    int y = ytile * 4 + (t >> 6);
    int xc = t & 63;
    float m[9];
    int aoff[9];
#pragma unroll
    for (int kh = 0; kh < 3; ++kh)
#pragma unroll
        for (int kw = 0; kw < 3; ++kw) {
            int yy = y + kh - 1, xx = xc + kw - 1;
            bool v = (yy >= 0 && yy < H && xx >= 0 && xx < W);
            int yyc = min(max(yy, 0), H - 1), xxc = min(max(xx, 0), W - 1);
            m[kh * 3 + kw] = v ? 1.f : 0.f;
            aoff[kh * 3 + kw] = yyc * W + xxc;
        }
    float a0 = ob[oc0], a1 = ob[oc0 + 1], a2 = ob[oc0 + 2];
    const float* xb = x + b * C * HW;
    for (int c = 0; c < C; ++c) {
        const float* xcp = xb + c * HW;
        const float* wc0 = &ws[c * 9];
        const float* wc1 = &ws[(C + c) * 9];
        const float* wc2 = &ws[(2 * C + c) * 9];
#pragma unroll
        for (int tp = 0; tp < 9; ++tp) {
            float v = m[tp] * xcp[aoff[tp]];
            a0 += v * wc0[tp];
            a1 += v * wc1[tp];
            a2 += v * wc2[tp];
        }
    }
    int rem = y * W + xc;
    offs[(b * 18 + oc0) * HW + rem] = a0;
    offs[(b * 18 + oc0 + 1) * HW + rem] = a1;
    offs[(b * 18 + oc0 + 2) * HW + rem] = a2;
}

// ---------------- kernel 2: bilinear sample + GEMM ----------------
// block: 32 pixels x 128 outputs, 256 threads; per thread 4 pixels x 4 outputs
__global__ __launch_bounds__(256) void deform_kernel(
    const float* __restrict__ x, const float* __restrict__ offs,
    const float* __restrict__ wT, const float* __restrict__ bias,
    float* __restrict__ out) {
    __shared__ float s_lds[CC][36];
    __shared__ float w_lds[CC][132];
    int t = threadIdx.x;
    int P0 = blockIdx.x * 32;
    int b = P0 >> 12;
    int rem0 = P0 & 4095;
    int y = rem0 >> 6; // whole block same row
    int x0 = rem0 & 63;
    int sp = t & 31;         // sampling: pixel
    int scc = (t >> 5) * 4;  // sampling: 4 cc's per thread
    int p4 = (t & 7) * 4;    // compute: pixel group
    int o4 = (t >> 3) * 4;   // compute: output group
    float4 acc[4];
#pragma unroll
    for (int j = 0; j < 4; ++j) {
        float bj = bias[o4 + j];
        acc[j] = make_float4(bj, bj, bj, bj);
    }
    const float* xb = x + b * C * HW;
    for (int k = 0; k < K2; ++k) {
        int kh = k / 3, kw = k % 3;
        int remp = rem0 + sp;
        float dy = offs[(b * 18 + 2 * k) * HW + remp];
        float dx = offs[(b * 18 + 2 * k + 1) * HW + remp];
        float ys = (float)(y - 1 + kh) + dy;
        float xs = (float)(x0 + sp - 1 + kw) + dx;
        float y0f = floorf(ys), x0f = floorf(xs);
        int iy0 = (int)y0f, ix0 = (int)x0f;
        int iy1 = iy0 + 1, ix1 = ix0 + 1;
        float wy1 = ys - y0f, wy0 = 1.f - wy1;
        float wx1 = xs - x0f, wx0 = 1.f - wx1;
        bool vy0 = (iy0 >= 0) & (iy0 < H), vy1 = (iy1 >= 0) & (iy1 < H);
        bool vx0 = (ix0 >= 0) & (ix0 < W), vx1 = (ix1 >= 0) & (ix1 < W);
        int iy0c = min(max(iy0, 0), H - 1), iy1c = min(max(iy1, 0), H - 1);
        int ix0c = min(max(ix0, 0), W - 1), ix1c = min(max(ix1, 0), W - 1);
        float w00 = (vy0 && vx0) ? wy0 * wx0 : 0.f;
        float w01 = (vy0 && vx1) ? wy0 * wx1 : 0.f;
        float w10 = (vy1 && vx0) ? wy1 * wx0 : 0.f;
        float w11 = (vy1 && vx1) ? wy1 * wx1 : 0.f;
        int a00 = iy0c * W + ix0c, a01 = iy0c * W + ix1c;
        int a10 = iy1c * W + ix0c, a11 = iy1c * W + ix1c;
        const float* wTk = wT + k * C * O;
        for (int ch = 0; ch < C / CC; ++ch) {
            __syncthreads();
            // stage weights: 32 x 128
#pragma unroll
            for (int i = 0; i < 4; ++i) {
                int flat = (i * 256 + t) * 4;
                int cc = flat >> 7;
                int oo = flat & 127;
                *(float4*)&w_lds[cc][oo] = *(const float4*)&wTk[(ch * CC + cc) * O + oo];
            }
            // stage bilinear samples: 32 pixels x 32 cc
#pragma unroll
            for (int i = 0; i < 4; ++i) {
                int cc = scc + i;
                const float* xcp = xb + (ch * CC + cc) * HW;
                float v = w00 * xcp[a00] + w01 * xcp[a01] + w10 * xcp[a10] + w11 * xcp[a11];
                s_lds[cc][sp] = v;
            }
            __syncthreads();
#pragma unroll
            for (int cc = 0; cc < CC; ++cc) {
                float4 s4 = *(const float4*)&s_lds[cc][p4];
                float4 w4 = *(const float4*)&w_lds[cc][o4];
                acc[0].x += s4.x * w4.x; acc[0].y += s4.y * w4.x; acc[0].z += s4.z * w4.x; acc[0].w += s4.w * w4.x;
                acc[1].x += s4.x * w4.y; acc[1].y += s4.y * w4.y; acc[1].z += s4.z * w4.y; acc[1].w += s4.w * w4.y;
                acc[2].x += s4.x * w4.z; acc[2].y += s4.y * w4.z; acc[2].z += s4.z * w4.z; acc[2].w += s4.w * w4.z;
                acc[3].x += s4.x * w4.w; acc[3].y += s4.y * w4.w; acc[3].z += s4.z * w4.w; acc[3].w += s4.w * w4.w;
            }
        }
    }
#pragma unroll
    for (int j = 0; j < 4; ++j) {
        *(float4*)&out[(b * O + o4 + j) * HW + rem0 + p4] = acc[j];
    }
}

extern "C" void kernel_launch(void* const* d_in, const int* in_sizes, int n_in,
                              void* d_out, int out_size, void* d_ws, size_t ws_size,
                              hipStream_t stream) {
    const float* x        = (const float*)d_in[0];
    const float* offset_w = (const float*)d_in[1];
    const float* offset_b = (const float*)d_in[2];
    const float* weight   = (const float*)d_in[3];
    const float* bias     = (const float*)d_in[4];
    float* out = (float*)d_out;
    float* offs = (float*)d_ws;                 // B*18*HW floats
    float* wT = offs + B * 18 * HW;             // 9*128*128 floats

    wtrans_kernel<<<(K2 * C * O) / 256, 256, 0, stream>>>(weight, wT);
    offconv_kernel<<<B * 6 * (H / 4), 256, 0, stream>>>(x, offset_w, offset_b, offs);
    deform_kernel<<<(B * HW) / 32, 256, 0, stream>>>(x, offs, wT, bias, out);
}

// Round 2
// 271.780 us; speedup vs baseline: 1.1312x; 1.1312x over previous
//
#include <hip/hip_runtime.h>

constexpr int B = 8, C = 128, H = 64, W = 64, O = 128;
constexpr int K2 = 9;
constexpr int HW = H * W; // 4096
constexpr int CC = 32;    // c-chunk in deform GEMM

// ---------------- kernel 0a: weight transpose: wT[k][c][o] = weight[o][c][k]
__global__ void wtrans_kernel(const float* __restrict__ w, float* __restrict__ wT) {
    int idx = blockIdx.x * 256 + threadIdx.x; // [0, 9*128*128)
    int o = idx & 127;
    int c = (idx >> 7) & 127;
    int k = idx >> 14;
    wT[idx] = w[(o * C + c) * 9 + k];
}

// ---------------- kernel 0b: offset-weight transpose: owT[c][tap][20(pad of 18)] = ow[oc][c][tap]
__global__ void otrans_kernel(const float* __restrict__ ow, float* __restrict__ owT) {
    int idx = blockIdx.x * 256 + threadIdx.x; // [0, 128*9*18)
    if (idx >= C * 9 * 18) return;
    int oc = idx % 18;
    int tap = (idx / 18) % 9;
    int c = idx / (18 * 9);
    owT[(c * 9 + tap) * 20 + oc] = ow[(oc * C + c) * 9 + tap];
}

// ---------------- kernel 1: offset conv (18 out-ch, 3x3, pad=1) ----------------
// block = 256 thr = 64 px (one row) x 4 c-groups of 32; grid = B*H
__global__ __launch_bounds__(256) void offconv_kernel(
    const float* __restrict__ x, const float* __restrict__ owT,
    const float* __restrict__ ob, float* __restrict__ offs) {
    __shared__ float s_red[4][18][64];
    int t = threadIdx.x;
    int bid = blockIdx.x;
    int b = bid >> 6, y = bid & 63;
    int px = t & 63;
    int cg = __builtin_amdgcn_readfirstlane(t >> 6);
    float m[9];
    int aoff[9];
#pragma unroll
    for (int kh = 0; kh < 3; ++kh)
#pragma unroll
        for (int kw = 0; kw < 3; ++kw) {
            int yy = y + kh - 1, xx = px + kw - 1;
            bool v = (yy >= 0 && yy < H && xx >= 0 && xx < W);
            m[kh * 3 + kw] = v ? 1.f : 0.f;
            aoff[kh * 3 + kw] = min(max(yy, 0), H - 1) * W + min(max(xx, 0), W - 1);
        }
    float acc[18];
#pragma unroll
    for (int o = 0; o < 18; ++o) acc[o] = 0.f;
    const float* xb = x + (b * C + cg * 32) * HW;
    const float* wb = owT + cg * 32 * 9 * 20;
    for (int c = 0; c < 32; ++c) {
        const float* xp = xb + c * HW;
        const float* wp = wb + c * 9 * 20;
#pragma unroll
        for (int tp = 0; tp < 9; ++tp) {
            float xv = m[tp] * xp[aoff[tp]];
            float4 w0 = *(const float4*)&wp[tp * 20 + 0];
            float4 w1 = *(const float4*)&wp[tp * 20 + 4];
            float4 w2 = *(const float4*)&wp[tp * 20 + 8];
            float4 w3 = *(const float4*)&wp[tp * 20 + 12];
            float2 w4 = *(const float2*)&wp[tp * 20 + 16];
            acc[0] += xv * w0.x;  acc[1] += xv * w0.y;  acc[2] += xv * w0.z;  acc[3] += xv * w0.w;
            acc[4] += xv * w1.x;  acc[5] += xv * w1.y;  acc[6] += xv * w1.z;  acc[7] += xv * w1.w;
            acc[8] += xv * w2.x;  acc[9] += xv * w2.y;  acc[10] += xv * w2.z; acc[11] += xv * w2.w;
            acc[12] += xv * w3.x; acc[13] += xv * w3.y; acc[14] += xv * w3.z; acc[15] += xv * w3.w;
            acc[16] += xv * w4.x; acc[17] += xv * w4.y;
        }
    }
#pragma unroll
    for (int o = 0; o < 18; ++o) s_red[t >> 6][o][px] = acc[o];
    __syncthreads();
    for (int flat = t; flat < 18 * 64; flat += 256) {
        int oc = flat >> 6, p = flat & 63;
        float v = ob[oc] + s_red[0][oc][p] + s_red[1][oc][p] + s_red[2][oc][p] + s_red[3][oc][p];
        offs[(b * 18 + oc) * HW + y * W + p] = v;
    }
}

// ---------------- kernel 2: bilinear sample + GEMM ----------------
// block = 256 thr; 64 px (one row) x 128 outputs; per-thread 4px x 8o
// double-buffered over 36 (k,ch) chunks, 1 barrier per chunk
__global__ __launch_bounds__(256) void deform_kernel(
    const float* __restrict__ x, const float* __restrict__ offs,
    const float* __restrict__ wT, const float* __restrict__ bias,
    float* __restrict__ out) {
    __shared__ float s_buf[2][CC][64];
    __shared__ float w_buf[2][CC][O];
    int t = threadIdx.x;
    int bid = blockIdx.x; // b*64 + y
    int b = bid >> 6, y = bid & 63;
    int row0 = y * W;
    int px = t & 63;
    int cgs = t >> 6;        // sampling c-phase 0..3
    int px4 = (t & 15) * 4;  // compute pixel group
    int o8 = (t >> 4) * 8;   // compute output group
    const float* xb = x + b * C * HW;

    // persistent sampling state for the k currently being staged
    float w00, w01, w10, w11;
    int a00, a01, a10, a11;

    auto calc_addr = [&](int k) {
        int kh = k / 3, kw = k % 3;
        float dy = offs[(b * 18 + 2 * k) * HW + row0 + px];
        float dx = offs[(b * 18 + 2 * k + 1) * HW + row0 + px];
        float ys = (float)(y - 1 + kh) + dy;
        float xs = (float)(px - 1 + kw) + dx;
        float y0f = floorf(ys), x0f = floorf(xs);
        int iy0 = (int)y0f, ix0 = (int)x0f;
        int iy1 = iy0 + 1, ix1 = ix0 + 1;
        float wy1 = ys - y0f, wy0 = 1.f - wy1;
        float wx1 = xs - x0f, wx0 = 1.f - wx1;
        bool vy0 = (iy0 >= 0) & (iy0 < H), vy1 = (iy1 >= 0) & (iy1 < H);
        bool vx0 = (ix0 >= 0) & (ix0 < W), vx1 = (ix1 >= 0) & (ix1 < W);
        int iy0c = min(max(iy0, 0), H - 1), iy1c = min(max(iy1, 0), H - 1);
        int ix0c = min(max(ix0, 0), W - 1), ix1c = min(max(ix1, 0), W - 1);
        w00 = (vy0 && vx0) ? wy0 * wx0 : 0.f;
        w01 = (vy0 && vx1) ? wy0 * wx1 : 0.f;
        w10 = (vy1 && vx0) ? wy1 * wx0 : 0.f;
        w11 = (vy1 && vx1) ? wy1 * wx1 : 0.f;
        a00 = iy0c * W + ix0c;
        a01 = iy0c * W + ix1c;
        a10 = iy1c * W + ix0c;
        a11 = iy1c * W + ix1c;
    };

    auto stage = [&](int idx, int bufi) {
        int k = idx >> 2, ch = idx & 3;
        if ((idx & 3) == 0) calc_addr(k);
        const float* wp = wT + (k * C + ch * CC) * O;
#pragma unroll
        for (int i = 0; i < 4; ++i) {
            int flat = (i * 256 + t) * 4;
            int cc = flat >> 7, oo = flat & 127;
            *(float4*)&w_buf[bufi][cc][oo] = *(const float4*)&wp[cc * O + oo];
        }
#pragma unroll
        for (int i = 0; i < 8; ++i) {
            int cc = cgs + i * 4;
            const float* p = xb + (ch * CC + cc) * HW;
            s_buf[bufi][cc][px] = w00 * p[a00] + w01 * p[a01] + w10 * p[a10] + w11 * p[a11];
        }
    };

    float4 acc[8];
#pragma unroll
    for (int j = 0; j < 8; ++j) {
        float bj = bias[o8 + j];
        acc[j] = make_float4(bj, bj, bj, bj);
    }

    stage(0, 0);
    __syncthreads();
#pragma unroll 1
    for (int i = 0; i < 36; ++i) {
        if (i < 35) stage(i + 1, (i + 1) & 1);
        int bufi = i & 1;
#pragma unroll
        for (int cc = 0; cc < CC; ++cc) {
            float4 s4 = *(const float4*)&s_buf[bufi][cc][px4];
            float4 wa = *(const float4*)&w_buf[bufi][cc][o8];
            float4 wb = *(const float4*)&w_buf[bufi][cc][o8 + 4];
            acc[0].x += s4.x * wa.x; acc[0].y += s4.y * wa.x; acc[0].z += s4.z * wa.x; acc[0].w += s4.w * wa.x;
            acc[1].x += s4.x * wa.y; acc[1].y += s4.y * wa.y; acc[1].z += s4.z * wa.y; acc[1].w += s4.w * wa.y;
            acc[2].x += s4.x * wa.z; acc[2].y += s4.y * wa.z; acc[2].z += s4.z * wa.z; acc[2].w += s4.w * wa.z;
            acc[3].x += s4.x * wa.w; acc[3].y += s4.y * wa.w; acc[3].z += s4.z * wa.w; acc[3].w += s4.w * wa.w;
            acc[4].x += s4.x * wb.x; acc[4].y += s4.y * wb.x; acc[4].z += s4.z * wb.x; acc[4].w += s4.w * wb.x;
            acc[5].x += s4.x * wb.y; acc[5].y += s4.y * wb.y; acc[5].z += s4.z * wb.y; acc[5].w += s4.w * wb.y;
            acc[6].x += s4.x * wb.z; acc[6].y += s4.y * wb.z; acc[6].z += s4.z * wb.z; acc[6].w += s4.w * wb.z;
            acc[7].x += s4.x * wb.w; acc[7].y += s4.y * wb.w; acc[7].z += s4.z * wb.w; acc[7].w += s4.w * wb.w;
        }
        __syncthreads();
    }

    int outb = (b * O + o8) * HW + row0 + px4;
#pragma unroll
    for (int j = 0; j < 8; ++j) {
        *(float4*)&out[outb + j * HW] = acc[j];
    }
}

extern "C" void kernel_launch(void* const* d_in, const int* in_sizes, int n_in,
                              void* d_out, int out_size, void* d_ws, size_t ws_size,
                              hipStream_t stream) {
    const float* x        = (const float*)d_in[0];
    const float* offset_w = (const float*)d_in[1];
    const float* offset_b = (const float*)d_in[2];
    const float* weight   = (const float*)d_in[3];
    const float* bias     = (const float*)d_in[4];
    float* out = (float*)d_out;
    float* offs = (float*)d_ws;                 // B*18*HW floats
    float* wT = offs + B * 18 * HW;             // 9*128*128 floats
    float* owT = wT + K2 * C * O;               // 128*9*20 floats

    wtrans_kernel<<<(K2 * C * O) / 256, 256, 0, stream>>>(weight, wT);
    otrans_kernel<<<(C * 9 * 18 + 255) / 256, 256, 0, stream>>>(offset_w, owT);
    offconv_kernel<<<B * H, 256, 0, stream>>>(x, owT, offset_b, offs);
    deform_kernel<<<B * H, 256, 0, stream>>>(x, offs, wT, bias, out);
}